// Round 11
// baseline (47.455 us; speedup 1.0000x reference)
//
#include <hip/hip_runtime.h>
#include <math.h>

#define HW 1024
#define PLANE (1024 * 1024)

typedef float vf4 __attribute__((ext_vector_type(4)));

// 9 possible grids (n in {20,30,40,65,80,95,125,150,175}), all compile-time:
//   g:      0    1    2    3    4    5    6    7    8
//   n:     20   30   40   65   80   95  125  150  175
//   gr:     4    5    6    8    9   10   11   12   13
//   gc:     5    6    7    9    9   10   12   13   14
// Unique column structures (gc): {5,6,7,9,10,12,13,14} -> 8 structures,
// 76 total col-cells, 84 boundary entries (incl. 0 and 1024).
__constant__ int GCS[8]   = {5, 6, 7, 9, 10, 12, 13, 14};
__constant__ int BBASE[8] = {0, 6, 13, 21, 31, 42, 55, 69};
__constant__ int GR9c[9]      = {4, 5, 6, 8, 9, 10, 11, 12, 13};
__constant__ int GC9c[9]      = {5, 6, 7, 9, 9, 10, 12, 13, 14};
__constant__ int COLBASE9c[9] = {0, 5, 11, 18, 18, 27, 37, 49, 62};

// ws layout (float units):
// [0..512)         per-block GLCM partials (64 blocks/batch * 8 batches)
// [16384..671744)  per-row column-cell records: 8 * 1024 rows * 80 (76 used)
//
// r5/r7 lessons: no grid-wide sync / device fences (10x cost on 8 XCDs).
// r9 lesson: redundant per-block recompute replaces a dispatch.
// r10 lesson: occupancy was not the limiter; this round: latency-bound
// one-shot waves -> persistent waves with cross-row register double-buffer.

__device__ __forceinline__ int wave_reduce_int(int v) {
#pragma unroll
    for (int off = 32; off > 0; off >>= 1) v += __shfl_down(v, off, 64);
    return v;
}
__device__ __forceinline__ float wave_reduce_f(float v) {
#pragma unroll
    for (int off = 32; off > 0; off >>= 1) v += __shfl_down(v, off, 64);
    return v;
}

__device__ __forceinline__ unsigned short f2bf(float x) {
    unsigned int u = __float_as_uint(x);
    u += 0x7fff + ((u >> 16) & 1);  // round-to-nearest-even
    return (unsigned short)(u >> 16);
}
__device__ __forceinline__ float bf2f(unsigned short s) {
    return __uint_as_float(((unsigned int)s) << 16);
}

// Kernel 1: grid (64, 8); 4 waves/block; each wave owns 4 rows, software-
// pipelined: row i+1's 12 loads are issued BEFORE row i's compute (register
// double-buffer), so the load queue never drains across the wave's lifetime
// (one-shot waves were latency-bound: both VALU and HBM idle). Lane l owns
// float4 chunks #l..#l+192 of a row (contiguous 1KB wave accesses).
// Per row: GLCM sq-diff partial; channel-mean -> wave scan -> boundary
// prefixes -> 76 column-cell sums -> rowrec. cmS in bf16 (r10).
__global__ __launch_bounds__(256) void k_main(const float* __restrict__ img,
                                              float* __restrict__ partials,
                                              float* __restrict__ rowrec) {
    const int b = blockIdx.y;
    const int rb = blockIdx.x;  // 0..63, block owns rows rb*16..rb*16+15
    const int tid = threadIdx.x;
    const int lane = tid & 63;
    const int w = tid >> 6;

    const float* pb = img + (size_t)b * (3 * PLANE);

    __shared__ unsigned short cmS[4][1024];  // bf16 channel-mean row
    __shared__ float PS[4][260];
    __shared__ float BS[4][88];
    __shared__ int swred[4];

    const int coff[4] = {(lane << 2), ((64 + lane) << 2), ((128 + lane) << 2),
                         ((192 + lane) << 2)};

    // Prefetch row it=0.
    vf4 RA[4], GA[4], BA[4], RN[4], GN[4], BN[4];
    {
        const float* p = pb + ((rb << 4) + w) * HW;
#pragma unroll
        for (int j = 0; j < 4; ++j) {
            RA[j] = __builtin_nontemporal_load((const vf4*)(p + coff[j]));
            GA[j] = __builtin_nontemporal_load((const vf4*)(p + PLANE + coff[j]));
            BA[j] = __builtin_nontemporal_load((const vf4*)(p + 2 * PLANE + coff[j]));
        }
    }

    int acc = 0;

#pragma unroll
    for (int it = 0; it < 4; ++it) {
        const int row = (rb << 4) + (it << 2) + w;

        // Issue next row's loads before any compute on the current row.
        if (it < 3) {
            const float* pn = pb + (row + 4) * HW;
#pragma unroll
            for (int j = 0; j < 4; ++j) {
                RN[j] = __builtin_nontemporal_load((const vf4*)(pn + coff[j]));
                GN[j] = __builtin_nontemporal_load((const vf4*)(pn + PLANE + coff[j]));
                BN[j] = __builtin_nontemporal_load((const vf4*)(pn + 2 * PLANE + coff[j]));
            }
        }

        int pend = 0;
        float csum[4];

#pragma unroll
        for (int j = 0; j < 4; ++j) {
            const int c = coff[j];

            const float m0 = (RA[j].x + GA[j].x + BA[j].x) * (1.0f / 3.0f);
            const float m1 = (RA[j].y + GA[j].y + BA[j].y) * (1.0f / 3.0f);
            const float m2 = (RA[j].z + GA[j].z + BA[j].z) * (1.0f / 3.0f);
            const float m3 = (RA[j].w + GA[j].w + BA[j].w) * (1.0f / 3.0f);
            *(ushort4*)&cmS[w][c] = make_ushort4(f2bf(m0), f2bf(m1), f2bf(m2), f2bf(m3));
            csum[j] = (m0 + m1) + (m2 + m3);

            const float g0 = 0.299f * RA[j].x + 0.587f * GA[j].x + 0.114f * BA[j].x;
            const float g1 = 0.299f * RA[j].y + 0.587f * GA[j].y + 0.114f * BA[j].y;
            const float g2 = 0.299f * RA[j].z + 0.587f * GA[j].z + 0.114f * BA[j].z;
            const float g3 = 0.299f * RA[j].w + 0.587f * GA[j].w + 0.114f * BA[j].w;

            const int gi0 = min(max((int)(g0 * 255.0f), 0), 255);
            const int gi1 = min(max((int)(g1 * 255.0f), 0), 255);
            const int gi2 = min(max((int)(g2 * 255.0f), 0), 255);
            const int gi3 = min(max((int)(g3 * 255.0f), 0), 255);

            const int first0 = __shfl(gi0, 0, 64);      // lane 0's first element
            if (j > 0 && lane == 63) {
                const int d = pend - first0;            // seam: chunk 63 -> 64
                acc += d * d;
            }
            const int nxt = __shfl_down(gi0, 1, 64);    // next lane's first elem
            const int d0 = gi0 - gi1, d1 = gi1 - gi2, d2 = gi2 - gi3;
            acc += d0 * d0 + d1 * d1 + d2 * d2;
            if (lane != 63) {
                const int d = gi3 - nxt;
                acc += d * d;
            }
            pend = gi3;
        }

        // Exclusive prefix of chunk sums over the whole row (wave scan).
        float pre = 0.0f;
#pragma unroll
        for (int j = 0; j < 4; ++j) {
            float x = csum[j];
#pragma unroll
            for (int off = 1; off < 64; off <<= 1) {
                const float y = __shfl_up(x, off, 64);
                if (lane >= off) x += y;
            }
            PS[w][(j << 6) + lane] = pre + (x - csum[j]);
            pre += __shfl(x, 63, 64);
        }
        if (lane == 0) PS[w][256] = pre;  // row total (boundary col 1024)

        // Boundary prefixes B(c) for all 84 boundary entries (wave-local LDS).
#pragma unroll
        for (int rep = 0; rep < 2; ++rep) {
            const int bnd = lane + (rep << 6);
            if (bnd < 84) {
                const int sct = (bnd >= 6) + (bnd >= 13) + (bnd >= 21) + (bnd >= 31) +
                                (bnd >= 42) + (bnd >= 55) + (bnd >= 69);
                const int gc = GCS[sct];
                const int i = bnd - BBASE[sct];
                const int c = (i * 1024 + gc - 1) / gc;  // ceil(i*1024/gc)
                const int m = c & 3;
                const int cb = min(c & ~3, 1020);        // clamp for c==1024
                float Bp = PS[w][c >> 2];
                const float a0 = bf2f(cmS[w][cb]), a1 = bf2f(cmS[w][cb + 1]),
                            a2 = bf2f(cmS[w][cb + 2]);
                if (m > 0) Bp += a0;
                if (m > 1) Bp += a1;
                if (m > 2) Bp += a2;
                BS[w][bnd] = Bp;
            }
        }

        // Column-cell sums = adjacent boundary differences -> per-row record.
        float* rr = rowrec + (size_t)((b << 10) + row) * 80;
#pragma unroll
        for (int rep = 0; rep < 2; ++rep) {
            const int k = lane + (rep << 6);
            if (k < 76) {
                const int sct = (k >= 5) + (k >= 11) + (k >= 18) + (k >= 27) +
                                (k >= 37) + (k >= 49) + (k >= 62);
                const int bidx = k + sct;
                rr[k] = BS[w][bidx + 1] - BS[w][bidx];
            }
        }

        // Rotate buffers (full unroll -> pure register renaming).
        if (it < 3) {
#pragma unroll
            for (int j = 0; j < 4; ++j) {
                RA[j] = RN[j];
                GA[j] = GN[j];
                BA[j] = BN[j];
            }
        }
    }

    acc = wave_reduce_int(acc);  // exact int within block
    if (lane == 0) swred[w] = acc;
    __syncthreads();
    if (tid == 0)
        partials[(b << 6) + rb] = (float)(swred[0] + swred[1] + swred[2] + swred[3]);
}

// Kernel 2 (self-sufficient fill): grid (256, 3, 8); block = 4 rows of one
// (batch, map). Each block independently: (a) reduces the batch's 64 GLCM
// partials -> complexity/tier (identical in every block; L2-resident),
// (b) computes the 1-2 row-cells x gc cell means its rows need from rowrec,
// (c) writes 4 output rows (NT). Block (0,0,b) writes complexity+cluster_sets.
__global__ __launch_bounds__(256) void k_fill2(const float* __restrict__ partials,
                                               const float* __restrict__ rowrec,
                                               float* __restrict__ out) {
    const int rblk = blockIdx.x, jm = blockIdx.y, b = blockIdx.z;
    const int tid = threadIdx.x;
    const int lane = tid & 63, w = tid >> 6;

    __shared__ float compLDS[4];
    __shared__ int tierS;
    __shared__ float red[16][17];
    __shared__ float cmLDS[2][16];

    // (a) tier from GLCM partials (64 per batch).
    float v = (tid < 64) ? partials[(b << 6) + tid] : 0.0f;
    v = wave_reduce_f(v);
    if (lane == 0) compLDS[w] = v;
    __syncthreads();
    if (tid == 0) {
        const float cv = (compLDS[0] + compLDS[1] + compLDS[2] + compLDS[3]) *
                         (1.0f / (1024.0f * 1023.0f));
        const int tier = (cv < 50.0f) ? 0 : ((cv < 150.0f) ? 1 : 2);
        tierS = tier;
        if (rblk == 0 && jm == 0) {
            const size_t OFFC = (size_t)8 * 3 * PLANE;
            out[OFFC + b] = cv;
            const int kk = (tier == 0) ? 30 : ((tier == 1) ? 80 : 150);
            const int dd = (tier == 0) ? 10 : ((tier == 1) ? 15 : 25);
#pragma unroll
            for (int j = 0; j < 3; ++j)
                out[OFFC + 8 + b * 3 + j] = (float)(kk + (j - 1) * dd);  // int vals
        }
    }
    __syncthreads();

    const int g = tierS * 3 + jm;
    const int gr = GR9c[g], gc = GC9c[g], cb = COLBASE9c[g];
    const int row0 = rblk << 2;
    const int rc0 = (row0 * gr) >> 10;
    const int rc3 = ((row0 + 3) * gr) >> 10;  // <= rc0+1 (cells are >=78 rows)

    // (b) cell means for the touched row-cells.
    const int cc = tid & 15, rch = tid >> 4;
    for (int rc = rc0; rc <= rc3; ++rc) {
        const int r0 = (rc * 1024 + gr - 1) / gr;
        const int r1 = ((rc + 1) * 1024 + gr - 1) / gr;
        float s = 0.0f;
        if (cc < gc)
            for (int r = r0 + rch; r < r1; r += 16)
                s += rowrec[(size_t)((b << 10) + r) * 80 + cb + cc];
        red[rch][cc] = s;
        __syncthreads();
        if (rch == 0 && cc < gc) {
            float tot = 0.0f;
#pragma unroll
            for (int q = 0; q < 16; ++q) tot += red[q][cc];
            const int c0 = (cc * 1024 + gc - 1) / gc;
            const int c1 = ((cc + 1) * 1024 + gc - 1) / gc;
            const float area = (float)((r1 - r0) * (c1 - c0));
            cmLDS[rc - rc0][cc] = tot / area;
        }
        __syncthreads();
    }

    // (c) write 4 rows (never re-read -> nontemporal).
    const int col = tid << 2;
    const int i0 = (col * gc) >> 10, i1 = ((col + 1) * gc) >> 10;
    const int i2 = ((col + 2) * gc) >> 10, i3 = ((col + 3) * gc) >> 10;
    float* ob = out + ((size_t)(b * 3 + jm) << 20);
#pragma unroll
    for (int i = 0; i < 4; ++i) {
        const int row = row0 + i;
        const int rc = (row * gr) >> 10;
        const float* cm = cmLDS[rc - rc0];
        vf4 o;
        o.x = cm[i0];
        o.y = cm[i1];
        o.z = cm[i2];
        o.w = cm[i3];
        __builtin_nontemporal_store(o, (vf4*)(ob + row * HW + col));
    }
}

extern "C" void kernel_launch(void* const* d_in, const int* in_sizes, int n_in,
                              void* d_out, int out_size, void* d_ws, size_t ws_size,
                              hipStream_t stream) {
    const float* img = (const float*)d_in[0];
    float* out = (float*)d_out;
    float* ws = (float*)d_ws;

    float* partials = ws;       // 512 floats
    float* rowrec = ws + 16384; // 8*1024*80 floats (2.6 MB)

    k_main<<<dim3(64, 8), 256, 0, stream>>>(img, partials, rowrec);
    k_fill2<<<dim3(256, 3, 8), 256, 0, stream>>>(partials, rowrec, out);
}

// Round 12
// 44.889 us; speedup vs baseline: 1.0572x; 1.0572x over previous
//
#include <hip/hip_runtime.h>
#include <math.h>

#define HW 1024
#define PLANE (1024 * 1024)

typedef float vf4 __attribute__((ext_vector_type(4)));

// 9 possible grids (n in {20,30,40,65,80,95,125,150,175}), all compile-time:
//   g:      0    1    2    3    4    5    6    7    8
//   n:     20   30   40   65   80   95  125  150  175
//   gr:     4    5    6    8    9   10   11   12   13
//   gc:     5    6    7    9    9   10   12   13   14
// Unique column structures (gc): {5,6,7,9,10,12,13,14} -> 8 structures,
// 76 total col-cells, 84 boundary entries (incl. 0 and 1024).
__constant__ int GCS[8]   = {5, 6, 7, 9, 10, 12, 13, 14};
__constant__ int BBASE[8] = {0, 6, 13, 21, 31, 42, 55, 69};
__constant__ int GR9c[9]      = {4, 5, 6, 8, 9, 10, 11, 12, 13};
__constant__ int GC9c[9]      = {5, 6, 7, 9, 9, 10, 12, 13, 14};
__constant__ int COLBASE9c[9] = {0, 5, 11, 18, 18, 27, 37, 49, 62};

// ws layout (float units):
// [0..2048)        per-block GLCM partials (256 blocks/batch * 8 batches)
// [16384..671744)  per-row column-cell records: 8 * 1024 rows * 80 (76 used)
//
// Session ledger (what's proven on this chip):
//  r1: 8192 same-line device atomics = 114us stall -> never.
//  r2: per-instruction-contiguous wave access (lane-chunked) fixed 2x write
//      amplification + 45MB over-fetch.
//  r5: cg grid.sync on 1024 blocks = +400us -> never fuse across global barrier.
//  r7: per-block __threadfence (device-scope) = +430us -> never fence-fold.
//  r9: redundant per-block recompute from L2-resident data replaces a
//      dispatch cheaply (-1.5us) -> this structure.
//  r6/r8/r10/r11: MLP hoist / NT hints / LDS-halving / persistent-wave
//      pipeline on k_main all neutral -> k_main is at its practical limit.

__device__ __forceinline__ int wave_reduce_int(int v) {
#pragma unroll
    for (int off = 32; off > 0; off >>= 1) v += __shfl_down(v, off, 64);
    return v;
}
__device__ __forceinline__ float wave_reduce_f(float v) {
#pragma unroll
    for (int off = 32; off > 0; off >>= 1) v += __shfl_down(v, off, 64);
    return v;
}

// Kernel 1: grid (256, 8); 4 waves/block, one ROW per wave. Lane l owns float4
// chunks #l, #l+64, #l+128, #l+192 (every global load is a contiguous 1KB wave
// access). img is read ONCE -> nontemporal loads. Per row: GLCM sq-diff
// partial; channel-mean -> wave scan -> boundary prefixes -> 76 column-cell
// sums -> rowrec (cached: re-read by k_fill2).
__global__ __launch_bounds__(256) void k_main(const float* __restrict__ img,
                                              float* __restrict__ partials,
                                              float* __restrict__ rowrec) {
    const int b = blockIdx.y;
    const int tid = threadIdx.x;
    const int lane = tid & 63;
    const int w = tid >> 6;
    const int row = (blockIdx.x << 2) + w;

    const float* p = img + (size_t)b * (3 * PLANE) + row * HW;

    __shared__ float cmS[4][1024];
    __shared__ float PS[4][260];
    __shared__ float BS[4][88];
    __shared__ int swred[4];

    // Hoisted nontemporal loads: all 12 in flight before any dependent use.
    vf4 R[4], G[4], Bv[4];
#pragma unroll
    for (int j = 0; j < 4; ++j) {
        const int c = ((j << 6) + lane) << 2;
        R[j] = __builtin_nontemporal_load((const vf4*)(p + c));
        G[j] = __builtin_nontemporal_load((const vf4*)(p + PLANE + c));
        Bv[j] = __builtin_nontemporal_load((const vf4*)(p + 2 * PLANE + c));
    }

    int acc = 0;
    int pend = 0;
    float csum[4];

#pragma unroll
    for (int j = 0; j < 4; ++j) {
        const int c = ((j << 6) + lane) << 2;

        const float m0 = (R[j].x + G[j].x + Bv[j].x) * (1.0f / 3.0f);
        const float m1 = (R[j].y + G[j].y + Bv[j].y) * (1.0f / 3.0f);
        const float m2 = (R[j].z + G[j].z + Bv[j].z) * (1.0f / 3.0f);
        const float m3 = (R[j].w + G[j].w + Bv[j].w) * (1.0f / 3.0f);
        *(float4*)&cmS[w][c] = make_float4(m0, m1, m2, m3);
        csum[j] = (m0 + m1) + (m2 + m3);

        const float g0 = 0.299f * R[j].x + 0.587f * G[j].x + 0.114f * Bv[j].x;
        const float g1 = 0.299f * R[j].y + 0.587f * G[j].y + 0.114f * Bv[j].y;
        const float g2 = 0.299f * R[j].z + 0.587f * G[j].z + 0.114f * Bv[j].z;
        const float g3 = 0.299f * R[j].w + 0.587f * G[j].w + 0.114f * Bv[j].w;

        const int gi0 = min(max((int)(g0 * 255.0f), 0), 255);
        const int gi1 = min(max((int)(g1 * 255.0f), 0), 255);
        const int gi2 = min(max((int)(g2 * 255.0f), 0), 255);
        const int gi3 = min(max((int)(g3 * 255.0f), 0), 255);

        const int first0 = __shfl(gi0, 0, 64);      // lane 0's first element
        if (j > 0 && lane == 63) {
            const int d = pend - first0;            // seam: chunk 63 -> chunk 64
            acc += d * d;
        }
        const int nxt = __shfl_down(gi0, 1, 64);    // next lane's first element
        const int d0 = gi0 - gi1, d1 = gi1 - gi2, d2 = gi2 - gi3;
        acc += d0 * d0 + d1 * d1 + d2 * d2;
        if (lane != 63) {
            const int d = gi3 - nxt;
            acc += d * d;
        }
        pend = gi3;
    }

    // Exclusive prefix of chunk sums over the whole row (wave scan).
    float pre = 0.0f;
#pragma unroll
    for (int j = 0; j < 4; ++j) {
        float x = csum[j];
#pragma unroll
        for (int off = 1; off < 64; off <<= 1) {
            const float y = __shfl_up(x, off, 64);
            if (lane >= off) x += y;
        }
        PS[w][(j << 6) + lane] = pre + (x - csum[j]);  // exclusive prefix of chunk
        pre += __shfl(x, 63, 64);
    }
    if (lane == 0) PS[w][256] = pre;  // row total (boundary col 1024)

    // Boundary prefixes B(c) for all 84 boundary entries (wave-local LDS).
#pragma unroll
    for (int rep = 0; rep < 2; ++rep) {
        const int bnd = lane + (rep << 6);
        if (bnd < 84) {
            const int sct = (bnd >= 6) + (bnd >= 13) + (bnd >= 21) + (bnd >= 31) +
                            (bnd >= 42) + (bnd >= 55) + (bnd >= 69);
            const int gc = GCS[sct];
            const int i = bnd - BBASE[sct];
            const int c = (i * 1024 + gc - 1) / gc;  // ceil(i*1024/gc)
            const int m = c & 3;
            const int cb = min(c & ~3, 1020);        // clamp for c==1024 (m==0)
            float Bp = PS[w][c >> 2];
            const float a0 = cmS[w][cb], a1 = cmS[w][cb + 1], a2 = cmS[w][cb + 2];
            if (m > 0) Bp += a0;
            if (m > 1) Bp += a1;
            if (m > 2) Bp += a2;
            BS[w][bnd] = Bp;
        }
    }

    // Column-cell sums = adjacent boundary differences -> per-row record.
    float* rr = rowrec + (size_t)((b << 10) + row) * 80;
#pragma unroll
    for (int rep = 0; rep < 2; ++rep) {
        const int k = lane + (rep << 6);
        if (k < 76) {
            const int sct = (k >= 5) + (k >= 11) + (k >= 18) + (k >= 27) +
                            (k >= 37) + (k >= 49) + (k >= 62);
            const int bidx = k + sct;
            rr[k] = BS[w][bidx + 1] - BS[w][bidx];
        }
    }

    acc = wave_reduce_int(acc);  // exact int within block
    if (lane == 0) swred[w] = acc;
    __syncthreads();
    if (tid == 0)
        partials[(b << 8) + blockIdx.x] = (float)(swred[0] + swred[1] + swred[2] + swred[3]);
}

// Kernel 2 (self-sufficient fill): grid (256, 3, 8); block = 4 rows of one
// (batch, map). Each block independently: (a) reduces the batch's 256 GLCM
// partials -> complexity/tier (deterministic order -> identical in every
// block; 1KB L2-resident), (b) computes the 1-2 row-cells x gc cell means its
// rows need from rowrec (L2/L3-resident), (c) writes 4 output rows (NT).
// Block (0,0,b) also writes complexity + cluster_sets.
__global__ __launch_bounds__(256) void k_fill2(const float* __restrict__ partials,
                                               const float* __restrict__ rowrec,
                                               float* __restrict__ out) {
    const int rblk = blockIdx.x, jm = blockIdx.y, b = blockIdx.z;
    const int tid = threadIdx.x;
    const int lane = tid & 63, w = tid >> 6;

    __shared__ float compLDS[4];
    __shared__ int tierS;
    __shared__ float red[16][17];
    __shared__ float cmLDS[2][16];

    // (a) tier from GLCM partials.
    float v = partials[(b << 8) + tid];
    v = wave_reduce_f(v);
    if (lane == 0) compLDS[w] = v;
    __syncthreads();
    if (tid == 0) {
        const float cv = (compLDS[0] + compLDS[1] + compLDS[2] + compLDS[3]) *
                         (1.0f / (1024.0f * 1023.0f));
        const int tier = (cv < 50.0f) ? 0 : ((cv < 150.0f) ? 1 : 2);
        tierS = tier;
        if (rblk == 0 && jm == 0) {
            const size_t OFFC = (size_t)8 * 3 * PLANE;
            out[OFFC + b] = cv;
            const int kk = (tier == 0) ? 30 : ((tier == 1) ? 80 : 150);
            const int dd = (tier == 0) ? 10 : ((tier == 1) ? 15 : 25);
#pragma unroll
            for (int j = 0; j < 3; ++j)
                out[OFFC + 8 + b * 3 + j] = (float)(kk + (j - 1) * dd);  // int vals, f32 buf
        }
    }
    __syncthreads();

    const int g = tierS * 3 + jm;
    const int gr = GR9c[g], gc = GC9c[g], cb = COLBASE9c[g];
    const int row0 = rblk << 2;
    const int rc0 = (row0 * gr) >> 10;
    const int rc3 = ((row0 + 3) * gr) >> 10;  // <= rc0+1 (cells are >=78 rows)

    // (b) cell means for the touched row-cells.
    const int cc = tid & 15, rch = tid >> 4;
    for (int rc = rc0; rc <= rc3; ++rc) {
        const int r0 = (rc * 1024 + gr - 1) / gr;
        const int r1 = ((rc + 1) * 1024 + gr - 1) / gr;
        float s = 0.0f;
        if (cc < gc)
            for (int r = r0 + rch; r < r1; r += 16)
                s += rowrec[(size_t)((b << 10) + r) * 80 + cb + cc];
        red[rch][cc] = s;
        __syncthreads();
        if (rch == 0 && cc < gc) {
            float tot = 0.0f;
#pragma unroll
            for (int q = 0; q < 16; ++q) tot += red[q][cc];
            const int c0 = (cc * 1024 + gc - 1) / gc;
            const int c1 = ((cc + 1) * 1024 + gc - 1) / gc;
            const float area = (float)((r1 - r0) * (c1 - c0));
            cmLDS[rc - rc0][cc] = tot / area;
        }
        __syncthreads();
    }

    // (c) write 4 rows (never re-read -> nontemporal).
    const int col = tid << 2;
    const int i0 = (col * gc) >> 10, i1 = ((col + 1) * gc) >> 10;
    const int i2 = ((col + 2) * gc) >> 10, i3 = ((col + 3) * gc) >> 10;
    float* ob = out + ((size_t)(b * 3 + jm) << 20);
#pragma unroll
    for (int i = 0; i < 4; ++i) {
        const int row = row0 + i;
        const int rc = (row * gr) >> 10;
        const float* cm = cmLDS[rc - rc0];
        vf4 o;
        o.x = cm[i0];
        o.y = cm[i1];
        o.z = cm[i2];
        o.w = cm[i3];
        __builtin_nontemporal_store(o, (vf4*)(ob + row * HW + col));
    }
}

extern "C" void kernel_launch(void* const* d_in, const int* in_sizes, int n_in,
                              void* d_out, int out_size, void* d_ws, size_t ws_size,
                              hipStream_t stream) {
    const float* img = (const float*)d_in[0];
    float* out = (float*)d_out;
    float* ws = (float*)d_ws;

    float* partials = ws;       // 2048 floats
    float* rowrec = ws + 16384; // 8*1024*80 floats (2.6 MB)

    k_main<<<dim3(256, 8), 256, 0, stream>>>(img, partials, rowrec);
    k_fill2<<<dim3(256, 3, 8), 256, 0, stream>>>(partials, rowrec, out);
}